// Round 1
// 129.362 us; speedup vs baseline: 1.0010x; 1.0010x over previous
//
#include <hip/hip_runtime.h>
#include <math.h>

#define Bn 4
#define Nn 1024
#define En 65536
#define Fn 96
#define FEn 32
#define Hn 12
// K dim for message MLP: 2F+FE = 224

// ---- out layout (floats) ----
#define OUT_UPD  0
#define OUT_WM   393216LL             // B*N*F
#define OUT_DIST 25559040LL           // + B*E*F
#define OUT_EDGE 25821184LL           // + B*E

// ---- ws layout (float words) ----
#define WS_AGG 0
#define WS_Q   393216
#define WS_K   786432
#define WS_V   1179648
#define WS_G   1572864
#define WS_AO  1966080

// q/k/v/g/ao live in ws as HEAD-MAJOR [B,H,N,8]; 4*12*1024*8 = 393216 floats.

__device__ __forceinline__ float gelu_exact(float x) {
    return 0.5f * x * (1.0f + erff(x * 0.70710678118654752f));
}

// Pass 0: zero agg with coalesced float4 stores. Replaces hipMemsetAsync,
// whose captured rocclr fillBufferAligned ran at ~25 GB/s (62 us for 1.5 MB).
// 192 blocks * 256 thr * 2 float4 = 98304 float4 = B*N*F floats.
__global__ void zero_kernel(float* __restrict__ agg) {
    int i = blockIdx.x * 256 + threadIdx.x;
    const float4 z = make_float4(0.f, 0.f, 0.f, 0.f);
    float4* p = (float4*)agg;
    p[i] = z;
    p[i + 49152] = z;
}

// Pass 1 (FUSED scan+msg): per block of 256 edges:
//   - zero this block's out_wm slice (coalesced float4)
//   - copy dist/edges to output, gaussian weight, LDS compaction (no global lists)
//   - msg phase: one wave per active edge: gather -> 224x96 matvec -> GELU ->
//     LayerNorm -> weight -> write wm row + atomic scatter into agg.
__global__ void scanmsg_kernel(const float* __restrict__ dist, const int* __restrict__ edges,
                               const float* __restrict__ sigma, const float* __restrict__ beta,
                               const float* __restrict__ nodes, const float* __restrict__ ef,
                               const float* __restrict__ Wm, const float* __restrict__ bm,
                               const float* __restrict__ g1, const float* __restrict__ b1,
                               float* __restrict__ out_dist, float* __restrict__ out_edges,
                               float* __restrict__ out_wm, float* __restrict__ agg) {
    __shared__ int   s_ge[256];
    __shared__ float s_w[256];
    __shared__ int   wcnt[4], wbase[4];
    __shared__ float sin_s[4][232];
    int tid = threadIdx.x;
    int blk = blockIdx.x;                 // 0 .. 1023
    int ge = blk * 256 + tid;             // 0 .. B*E-1

    // ---- zero out_wm slice: 256 edges * 96 floats ----
    const float4 z = make_float4(0.f, 0.f, 0.f, 0.f);
    float4* wm4 = (float4*)(out_wm + (size_t)blk * 24576);
    #pragma unroll
    for (int i = 0; i < 24; ++i)
        wm4[i * 256 + tid] = z;

    // ---- per-edge scan ----
    float d = dist[ge];
    out_dist[ge] = d;
    int e0s = edges[2 * ge], e1s = edges[2 * ge + 1];
    *(float2*)&out_edges[2 * ge] = make_float2((float)e0s, (float)e1s);
    float sg = sigma[0], bt = beta[0];
    float t  = d * d / (2.0f * sg * sg);
    float tp = powf(t, bt);
    bool active = (tp < 90.0f);            // else w underflows f32 (ref < 1e-39)
    float w = active ? expf(-tp) : 0.0f;

    unsigned long long mask = __ballot(active);
    int lane = tid & 63, wv = tid >> 6;
    int lp = __popcll(mask & ((1ull << lane) - 1ull));
    if (lane == 0) wcnt[wv] = __popcll(mask);
    __syncthreads();
    if (tid == 0) {
        int a = 0;
        #pragma unroll
        for (int i = 0; i < 4; ++i) { wbase[i] = a; a += wcnt[i]; }
    }
    __syncthreads();
    if (active) {
        int pos = wbase[wv] + lp;
        s_ge[pos] = ge;
        s_w[pos]  = w;
    }
    __syncthreads();
    int count = wbase[3] + wcnt[3];

    // ---- msg phase: wave wv handles actives wv, wv+4, ... ----
    int c2 = 64 + (lane & 31);             // upper lanes duplicate lanes 0..31
    for (int ai = wv; ai < count; ai += 4) {
        int gei = s_ge[ai];
        float wgt = s_w[ai];
        int b = gei >> 16;
        int e0 = edges[2 * gei], e1 = edges[2 * gei + 1];
        const float* n0 = nodes + ((size_t)b * Nn + e0) * 96;
        const float* n1 = nodes + ((size_t)b * Nn + e1) * 96;
        const float* ep = ef + (size_t)gei * 32;
        #pragma unroll
        for (int ii = 0; ii < 4; ++ii) {
            int i = ii * 64 + lane;
            if (i < 224) {
                float v = (i < 96) ? n0[i] : (i < 192) ? n1[i - 96] : ep[i - 192];
                sin_s[wv][i] = v;
            }
        }
        // wave-local LDS: write->read same wave, ordered, no barrier
        float acc1 = bm[lane];
        float acc2 = bm[c2];
        #pragma unroll 8
        for (int i = 0; i < 224; ++i) {
            float a = sin_s[wv][i];                        // LDS broadcast
            acc1 = fmaf(a, Wm[i * 96 + lane], acc1);
            acc2 = fmaf(a, Wm[i * 96 + c2], acc2);
        }
        float y1 = gelu_exact(acc1);
        float y2 = gelu_exact(acc2);
        float c2v = (lane < 32) ? y2 : 0.0f;
        float sum  = y1 + c2v;
        float sum2 = y1 * y1 + c2v * c2v;
        #pragma unroll
        for (int off = 1; off < 64; off <<= 1) {
            sum  += __shfl_xor(sum, off);
            sum2 += __shfl_xor(sum2, off);
        }
        float mean = sum * (1.0f / 96.0f);
        float var  = sum2 * (1.0f / 96.0f) - mean * mean;
        float rs   = rsqrtf(var + 1e-3f);
        float* aggp = agg + ((size_t)b * Nn + e1) * 96;
        float* wmp  = out_wm + (size_t)gei * 96;
        float o1 = ((y1 - mean) * rs * g1[lane] + b1[lane]) * wgt;
        wmp[lane] = o1;
        atomicAdd(&aggp[lane], o1);
        if (lane < 32) {
            float o2 = ((y2 - mean) * rs * g1[c2] + b1[c2]) * wgt;
            wmp[c2] = o2;
            atomicAdd(&aggp[c2], o2);
        }
    }
}

// Pass 2: q/k/v/gate projections. x = [nodes, agg] (4096 x 192) @ W (192 x 96) + b.
// Output HEAD-MAJOR [B,H,N,8] via LDS re-stage -> fully coalesced float4 stores.
__global__ void proj_kernel(const float* __restrict__ nodes, const float* __restrict__ agg,
                            const float* __restrict__ Wq, const float* __restrict__ bq,
                            const float* __restrict__ Wk, const float* __restrict__ bk,
                            const float* __restrict__ Wv, const float* __restrict__ bv,
                            const float* __restrict__ Wg, const float* __restrict__ bg,
                            float* __restrict__ qo, float* __restrict__ ko,
                            float* __restrict__ vo, float* __restrict__ go) {
    __shared__ float xs[32][200];   // padded; row byte-stride 800 = 50*16 (16B aligned)
    __shared__ float Wt[64 * 96];
    int m = blockIdx.y;
    const float* W    = (m == 0) ? Wq : (m == 1) ? Wk : (m == 2) ? Wv : Wg;
    const float* bias = (m == 0) ? bq : (m == 1) ? bk : (m == 2) ? bv : bg;
    float* outp       = (m == 0) ? qo : (m == 1) ? ko : (m == 2) ? vo : go;
    int tid = threadIdx.x;
    int row0 = blockIdx.x * 32;
    int b = row0 >> 10, n0 = row0 & 1023;
    for (int i = tid; i < 32 * 192; i += 256) {
        int r = i / 192, k = i % 192;
        size_t row = row0 + r;
        xs[r][k] = (k < 96) ? nodes[row * 96 + k] : agg[row * 96 + (k - 96)];
    }
    int rg = tid >> 4;              // 0..15 (2 rows each)
    int cg = tid & 15;              // 0..15 (6 cols each)
    float acc[12];
    #pragma unroll
    for (int c = 0; c < 12; ++c) acc[c] = 0.0f;
    for (int kc = 0; kc < 3; ++kc) {
        __syncthreads();
        {
            float4* Wt4 = (float4*)Wt;
            const float4* Wg4 = (const float4*)(W + kc * 64 * 96);
            for (int i = tid; i < 1536; i += 256) Wt4[i] = Wg4[i];
        }
        __syncthreads();
        #pragma unroll 4
        for (int k = 0; k < 64; ++k) {
            float a0 = xs[rg * 2 + 0][kc * 64 + k];
            float a1 = xs[rg * 2 + 1][kc * 64 + k];
            #pragma unroll
            for (int c = 0; c < 6; ++c) {
                float wv_ = Wt[k * 96 + cg * 6 + c];
                acc[c]     = fmaf(a0, wv_, acc[c]);
                acc[6 + c] = fmaf(a1, wv_, acc[6 + c]);
            }
        }
    }
    // epilogue into LDS (cols 0..95 don't overlap kc=2's read range 128..191)
    #pragma unroll
    for (int i = 0; i < 2; ++i) {
        #pragma unroll
        for (int c = 0; c < 6; ++c) {
            int col = cg * 6 + c;
            float v = acc[i * 6 + c] + bias[col];
            if (m == 3) v = 1.0f / (1.0f + expf(-v));
            xs[rg * 2 + i][col] = v;
        }
    }
    __syncthreads();
    // coalesced store: per head h, 32 rows * 8 floats = contiguous 64 float4
    float4* out4 = (float4*)outp;
    for (int j = tid; j < 768; j += 256) {
        int h = j >> 6, idx = j & 63;
        int r = idx >> 1, half = idx & 1;
        float4 v = *(const float4*)&xs[r][h * 8 + half * 4];
        out4[(((size_t)b * Hn + h) * Nn + n0) * 2 + idx] = v;
    }
}

// Pass 3: split-KV attention, head-major. 8 waves/block, 128 keys/wave,
// 4-key groups; K/V time-share one 8xfloat4 register block (VGPR diet ->
// 3 blocks/CU, 6 waves/SIMD, 768 blocks = exactly one occupancy round).
__global__ __launch_bounds__(512, 6) void attn_kernel(
        const float* __restrict__ qp, const float* __restrict__ kp,
        const float* __restrict__ vp, const float* __restrict__ gp,
        float* __restrict__ ao) {
    __shared__ float sm[512], sl[512];
    __shared__ float sacc[512][9];
    int bh = blockIdx.y;                    // b*H + h
    int tid = threadIdx.x;
    int lane = tid & 63;
    int w = __builtin_amdgcn_readfirstlane(tid >> 6);
    int n = blockIdx.x * 64 + lane;
    size_t hb = (size_t)bh * (Nn * 8);
    size_t qoff = hb + (size_t)n * 8;

    const float scale = 0.35355339059327376f;  // 1/sqrt(8)
    float4 q0 = *(const float4*)&qp[qoff];
    float4 q1 = *(const float4*)&qp[qoff + 4];
    q0.x *= scale; q0.y *= scale; q0.z *= scale; q0.w *= scale;
    q1.x *= scale; q1.y *= scale; q1.z *= scale; q1.w *= scale;

    const float4* kc4 = (const float4*)(kp + hb) + (size_t)w * 256;  // 128 keys
    const float4* vc4 = (const float4*)(vp + hb) + (size_t)w * 256;

    float m = -1e30f, l = 0.0f;
    float a0 = 0, a1 = 0, a2 = 0, a3 = 0, a4 = 0, a5 = 0, a6 = 0, a7 = 0;
    for (int g = 0; g < 32; ++g) {          // 4 keys per group
        float4 T[8];
        #pragma unroll
        for (int i = 0; i < 8; ++i) T[i] = kc4[g * 8 + i];   // K group
        float s[4];
        #pragma unroll
        for (int jj = 0; jj < 4; ++jj) {
            float4 k0 = T[jj * 2], k1 = T[jj * 2 + 1];
            s[jj] = q0.x * k0.x + q0.y * k0.y + q0.z * k0.z + q0.w * k0.w +
                    q1.x * k1.x + q1.y * k1.y + q1.z * k1.z + q1.w * k1.w;
        }
        #pragma unroll
        for (int i = 0; i < 8; ++i) T[i] = vc4[g * 8 + i];   // reuse regs: V group
        float mx = fmaxf(fmaxf(s[0], s[1]), fmaxf(s[2], s[3]));
        float nm = fmaxf(m, mx);
        float corr = __expf(m - nm);
        float p[4];
        #pragma unroll
        for (int jj = 0; jj < 4; ++jj) p[jj] = __expf(s[jj] - nm);
        l = l * corr + (p[0] + p[1]) + (p[2] + p[3]);
        a0 *= corr; a1 *= corr; a2 *= corr; a3 *= corr;
        a4 *= corr; a5 *= corr; a6 *= corr; a7 *= corr;
        #pragma unroll
        for (int jj = 0; jj < 4; ++jj) {
            float4 v0 = T[jj * 2], v1 = T[jj * 2 + 1];
            a0 = fmaf(p[jj], v0.x, a0);  a1 = fmaf(p[jj], v0.y, a1);
            a2 = fmaf(p[jj], v0.z, a2);  a3 = fmaf(p[jj], v0.w, a3);
            a4 = fmaf(p[jj], v1.x, a4);  a5 = fmaf(p[jj], v1.y, a5);
            a6 = fmaf(p[jj], v1.z, a6);  a7 = fmaf(p[jj], v1.w, a7);
        }
        m = nm;
    }
    sm[tid] = m;
    sl[tid] = l;
    sacc[tid][0] = a0; sacc[tid][1] = a1; sacc[tid][2] = a2; sacc[tid][3] = a3;
    sacc[tid][4] = a4; sacc[tid][5] = a5; sacc[tid][6] = a6; sacc[tid][7] = a7;
    __syncthreads();
    if (tid < 64) {
        float M = sm[tid];
        #pragma unroll
        for (int i = 1; i < 8; ++i) M = fmaxf(M, sm[tid + 64 * i]);
        float L = 0.0f;
        float o[8] = {0, 0, 0, 0, 0, 0, 0, 0};
        #pragma unroll
        for (int i = 0; i < 8; ++i) {
            float e = __expf(sm[tid + 64 * i] - M);
            L = fmaf(sl[tid + 64 * i], e, L);
            #pragma unroll
            for (int d = 0; d < 8; ++d)
                o[d] = fmaf(sacc[tid + 64 * i][d], e, o[d]);
        }
        float invL = 1.0f / L;
        float4 g0 = *(const float4*)&gp[qoff];
        float4 g1v = *(const float4*)&gp[qoff + 4];
        float4 r0 = make_float4(o[0] * invL * g0.x, o[1] * invL * g0.y,
                                o[2] * invL * g0.z, o[3] * invL * g0.w);
        float4 r1 = make_float4(o[4] * invL * g1v.x, o[5] * invL * g1v.y,
                                o[6] * invL * g1v.z, o[7] * invL * g1v.w);
        *(float4*)&ao[qoff] = r0;
        *(float4*)&ao[qoff + 4] = r1;
    }
}

// Pass 4: out @ Wo + bo -> GELU -> LayerNorm. 512 thr, 32 rows/block,
// coalesced float4 gather of head-major ao via LDS.
__global__ __launch_bounds__(512) void out_kernel(
        const float* __restrict__ ao, const float* __restrict__ Wo,
        const float* __restrict__ bo, const float* __restrict__ g2,
        const float* __restrict__ b2, float* __restrict__ out0) {
    __shared__ float Wsh[96 * 96];
    __shared__ float as_[32][104];   // row byte-stride 416 = 26*16 (16B aligned)
    int tid = threadIdx.x;
    int row0 = blockIdx.x * 32;
    int b = row0 >> 10, n0 = row0 & 1023;
    {
        float4* W4 = (float4*)Wsh;
        const float4* Wg4 = (const float4*)Wo;
        for (int i = tid; i < 2304; i += 512) W4[i] = Wg4[i];
    }
    const float4* ao4 = (const float4*)ao;
    for (int j = tid; j < 768; j += 512) {
        int h = j >> 6, idx = j & 63;
        int r = idx >> 1, half = idx & 1;
        float4 v = ao4[(((size_t)b * Hn + h) * Nn + n0) * 2 + idx];
        *(float4*)&as_[r][h * 8 + half * 4] = v;
    }
    __syncthreads();
    int r = tid >> 4, cg = tid & 15;   // 32 rows, 6 cols per thread
    float acc[6];
    #pragma unroll
    for (int c = 0; c < 6; ++c) acc[c] = 0.0f;
    for (int k = 0; k < 96; ++k) {
        float a = as_[r][k];
        #pragma unroll
        for (int c = 0; c < 6; ++c)
            acc[c] = fmaf(a, Wsh[k * 96 + cg * 6 + c], acc[c]);
    }
    float yv[6];
    float sum = 0.0f, sum2 = 0.0f;
    #pragma unroll
    for (int c = 0; c < 6; ++c) {
        float t = acc[c] + bo[cg * 6 + c];
        float g = gelu_exact(t);
        yv[c] = g;
        sum += g; sum2 += g * g;
    }
    #pragma unroll
    for (int off = 1; off < 16; off <<= 1) {
        sum  += __shfl_xor(sum, off);
        sum2 += __shfl_xor(sum2, off);
    }
    float mean = sum * (1.0f / 96.0f);
    float var  = sum2 * (1.0f / 96.0f) - mean * mean;
    float rs   = rsqrtf(var + 1e-3f);
    size_t row = row0 + r;
    #pragma unroll
    for (int c = 0; c < 6; ++c)
        out0[row * 96 + cg * 6 + c] = (yv[c] - mean) * rs * g2[cg * 6 + c] + b2[cg * 6 + c];
}

extern "C" void kernel_launch(void* const* d_in, const int* in_sizes, int n_in,
                              void* d_out, int out_size, void* d_ws, size_t ws_size,
                              hipStream_t stream) {
    const float* nodes = (const float*)d_in[0];
    const float* ef    = (const float*)d_in[1];
    const float* dist  = (const float*)d_in[2];
    const int*   edges = (const int*)d_in[3];
    const float* Wm = (const float*)d_in[4];
    const float* bm = (const float*)d_in[5];
    const float* g1 = (const float*)d_in[6];
    const float* b1 = (const float*)d_in[7];
    const float* Wq = (const float*)d_in[8];
    const float* bq = (const float*)d_in[9];
    const float* Wk = (const float*)d_in[10];
    const float* bk = (const float*)d_in[11];
    const float* Wv = (const float*)d_in[12];
    const float* bv = (const float*)d_in[13];
    const float* Wg = (const float*)d_in[14];
    const float* bg = (const float*)d_in[15];
    const float* Wo = (const float*)d_in[16];
    const float* bo = (const float*)d_in[17];
    const float* g2 = (const float*)d_in[18];
    const float* b2 = (const float*)d_in[19];
    const float* sigma = (const float*)d_in[20];
    const float* beta  = (const float*)d_in[21];

    float* out = (float*)d_out;
    float* ws  = (float*)d_ws;

    float* agg  = ws + WS_AGG;
    float* qb   = ws + WS_Q;
    float* kb   = ws + WS_K;
    float* vb   = ws + WS_V;
    float* gwb  = ws + WS_G;
    float* aob  = ws + WS_AO;

    zero_kernel<<<192, 256, 0, stream>>>(agg);

    scanmsg_kernel<<<Bn * En / 256, 256, 0, stream>>>(
        dist, edges, sigma, beta, nodes, ef, Wm, bm, g1, b1,
        out + OUT_DIST, out + OUT_EDGE, out + OUT_WM, agg);

    dim3 gp_(128, 4);
    proj_kernel<<<gp_, 256, 0, stream>>>(
        nodes, agg, Wq, bq, Wk, bk, Wv, bv, Wg, bg, qb, kb, vb, gwb);

    dim3 ga(16, Bn * Hn);
    attn_kernel<<<ga, 512, 0, stream>>>(qb, kb, vb, gwb, aob);

    out_kernel<<<Bn * Nn / 32, 512, 0, stream>>>(aob, Wo, bo, g2, b2, out + OUT_UPD);
}

// Round 2
// 128.453 us; speedup vs baseline: 1.0080x; 1.0071x over previous
//
#include <hip/hip_runtime.h>
#include <math.h>

#define Bn 4
#define Nn 1024
#define En 65536
#define Fn 96
#define FEn 32
#define Hn 12
// K dim for message MLP: 2F+FE = 224

// ---- out layout (floats) ----
#define OUT_UPD  0
#define OUT_WM   393216LL             // B*N*F
#define OUT_DIST 25559040LL           // + B*E*F
#define OUT_EDGE 25821184LL           // + B*E

// ---- ws layout (float words) ----
#define WS_AGG 0
#define WS_Q   393216
#define WS_K   786432
#define WS_V   1179648
#define WS_G   1572864
#define WS_AO  1966080

// q/k/v/g/ao live in ws as HEAD-MAJOR [B,H,N,8]; 4*12*1024*8 = 393216 floats.

__device__ __forceinline__ float gelu_exact(float x) {
    return 0.5f * x * (1.0f + erff(x * 0.70710678118654752f));
}

// Zero the inactive rows of one 256-edge chunk of out_wm (96 KB).
// Active rows (tp < 90, ~1.2% of edges) were already written by scanmsg;
// the active test is the bitwise-identical expression, so the sets partition.
// Called at kernel START of the compute-bound kernels so the ~100 MB of zero
// stores drain under their VALU work instead of costing serial write-BW time.
__device__ __forceinline__ void zero_wm_chunk(int c, const float* __restrict__ dist,
                                              const float* __restrict__ sigma,
                                              const float* __restrict__ beta,
                                              float* __restrict__ out_wm,
                                              int tid, int nthr, int* s_act) {
    if (tid < 256) {
        int ge = c * 256 + tid;
        float d = dist[ge];
        float sg = sigma[0], bt = beta[0];
        float t = d * d / (2.0f * sg * sg);
        s_act[tid] = (powf(t, bt) < 90.0f) ? 1 : 0;
    }
    __syncthreads();
    const float4 z = make_float4(0.f, 0.f, 0.f, 0.f);
    float4* wm4 = (float4*)out_wm + (size_t)c * 6144;   // 256 rows * 24 float4
    for (int p = tid; p < 6144; p += nthr) {
        if (!s_act[p / 24]) wm4[p] = z;
    }
}

// Pass 0: zero agg with coalesced float4 stores (1.5 MB).
__global__ void zero_kernel(float* __restrict__ agg) {
    int i = blockIdx.x * 256 + threadIdx.x;
    const float4 z = make_float4(0.f, 0.f, 0.f, 0.f);
    float4* p = (float4*)agg;
    p[i] = z;
    p[i + 49152] = z;
}

// Pass 1 (FUSED scan+msg): per block of 256 edges:
//   - copy dist/edges to output, gaussian weight, LDS compaction (no global lists)
//   - msg phase: one wave per active edge: gather -> 224x96 matvec -> GELU ->
//     LayerNorm -> weight -> write wm row + atomic scatter into agg.
// (out_wm zero-fill of inactive rows moved into proj/attn/out kernels.)
__global__ void scanmsg_kernel(const float* __restrict__ dist, const int* __restrict__ edges,
                               const float* __restrict__ sigma, const float* __restrict__ beta,
                               const float* __restrict__ nodes, const float* __restrict__ ef,
                               const float* __restrict__ Wm, const float* __restrict__ bm,
                               const float* __restrict__ g1, const float* __restrict__ b1,
                               float* __restrict__ out_dist, float* __restrict__ out_edges,
                               float* __restrict__ out_wm, float* __restrict__ agg) {
    __shared__ int   s_ge[256];
    __shared__ float s_w[256];
    __shared__ int   wcnt[4], wbase[4];
    __shared__ float sin_s[4][232];
    int tid = threadIdx.x;
    int blk = blockIdx.x;                 // 0 .. 1023
    int ge = blk * 256 + tid;             // 0 .. B*E-1

    // ---- per-edge scan ----
    float d = dist[ge];
    out_dist[ge] = d;
    int e0s = edges[2 * ge], e1s = edges[2 * ge + 1];
    *(float2*)&out_edges[2 * ge] = make_float2((float)e0s, (float)e1s);
    float sg = sigma[0], bt = beta[0];
    float t  = d * d / (2.0f * sg * sg);
    float tp = powf(t, bt);
    bool active = (tp < 90.0f);            // else w underflows f32 (ref < 1e-39)
    float w = active ? expf(-tp) : 0.0f;

    unsigned long long mask = __ballot(active);
    int lane = tid & 63, wv = tid >> 6;
    int lp = __popcll(mask & ((1ull << lane) - 1ull));
    if (lane == 0) wcnt[wv] = __popcll(mask);
    __syncthreads();
    if (tid == 0) {
        int a = 0;
        #pragma unroll
        for (int i = 0; i < 4; ++i) { wbase[i] = a; a += wcnt[i]; }
    }
    __syncthreads();
    if (active) {
        int pos = wbase[wv] + lp;
        s_ge[pos] = ge;
        s_w[pos]  = w;
    }
    __syncthreads();
    int count = wbase[3] + wcnt[3];

    // ---- msg phase: wave wv handles actives wv, wv+4, ... ----
    int c2 = 64 + (lane & 31);             // upper lanes duplicate lanes 0..31
    for (int ai = wv; ai < count; ai += 4) {
        int gei = s_ge[ai];
        float wgt = s_w[ai];
        int b = gei >> 16;
        int e0 = edges[2 * gei], e1 = edges[2 * gei + 1];
        const float* n0 = nodes + ((size_t)b * Nn + e0) * 96;
        const float* n1 = nodes + ((size_t)b * Nn + e1) * 96;
        const float* ep = ef + (size_t)gei * 32;
        #pragma unroll
        for (int ii = 0; ii < 4; ++ii) {
            int i = ii * 64 + lane;
            if (i < 224) {
                float v = (i < 96) ? n0[i] : (i < 192) ? n1[i - 96] : ep[i - 192];
                sin_s[wv][i] = v;
            }
        }
        // wave-local LDS: write->read same wave, ordered, no barrier
        float acc1 = bm[lane];
        float acc2 = bm[c2];
        #pragma unroll 8
        for (int i = 0; i < 224; ++i) {
            float a = sin_s[wv][i];                        // LDS broadcast
            acc1 = fmaf(a, Wm[i * 96 + lane], acc1);
            acc2 = fmaf(a, Wm[i * 96 + c2], acc2);
        }
        float y1 = gelu_exact(acc1);
        float y2 = gelu_exact(acc2);
        float c2v = (lane < 32) ? y2 : 0.0f;
        float sum  = y1 + c2v;
        float sum2 = y1 * y1 + c2v * c2v;
        #pragma unroll
        for (int off = 1; off < 64; off <<= 1) {
            sum  += __shfl_xor(sum, off);
            sum2 += __shfl_xor(sum2, off);
        }
        float mean = sum * (1.0f / 96.0f);
        float var  = sum2 * (1.0f / 96.0f) - mean * mean;
        float rs   = rsqrtf(var + 1e-3f);
        float* aggp = agg + ((size_t)b * Nn + e1) * 96;
        float* wmp  = out_wm + (size_t)gei * 96;
        float o1 = ((y1 - mean) * rs * g1[lane] + b1[lane]) * wgt;
        wmp[lane] = o1;
        atomicAdd(&aggp[lane], o1);
        if (lane < 32) {
            float o2 = ((y2 - mean) * rs * g1[c2] + b1[c2]) * wgt;
            wmp[c2] = o2;
            atomicAdd(&aggp[c2], o2);
        }
    }
}

// Pass 2: q/k/v/gate projections. x = [nodes, agg] (4096 x 192) @ W (192 x 96) + b.
// Output HEAD-MAJOR [B,H,N,8] via LDS re-stage -> fully coalesced float4 stores.
// m=0 blocks additionally zero out_wm chunks [768, 896).
__global__ void proj_kernel(const float* __restrict__ nodes, const float* __restrict__ agg,
                            const float* __restrict__ Wq, const float* __restrict__ bq,
                            const float* __restrict__ Wk, const float* __restrict__ bk,
                            const float* __restrict__ Wv, const float* __restrict__ bv,
                            const float* __restrict__ Wg, const float* __restrict__ bg,
                            float* __restrict__ qo, float* __restrict__ ko,
                            float* __restrict__ vo, float* __restrict__ go,
                            const float* __restrict__ dist, const float* __restrict__ sigma,
                            const float* __restrict__ beta, float* __restrict__ out_wm) {
    __shared__ float xs[32][200];   // padded; row byte-stride 800 = 50*16 (16B aligned)
    __shared__ float Wt[64 * 96];
    __shared__ int s_act[256];
    int tid = threadIdx.x;
    int m = blockIdx.y;
    if (m == 0) {
        zero_wm_chunk(768 + blockIdx.x, dist, sigma, beta, out_wm, tid, 256, s_act);
    }
    const float* W    = (m == 0) ? Wq : (m == 1) ? Wk : (m == 2) ? Wv : Wg;
    const float* bias = (m == 0) ? bq : (m == 1) ? bk : (m == 2) ? bv : bg;
    float* outp       = (m == 0) ? qo : (m == 1) ? ko : (m == 2) ? vo : go;
    int row0 = blockIdx.x * 32;
    int b = row0 >> 10, n0 = row0 & 1023;
    for (int i = tid; i < 32 * 192; i += 256) {
        int r = i / 192, k = i % 192;
        size_t row = row0 + r;
        xs[r][k] = (k < 96) ? nodes[row * 96 + k] : agg[row * 96 + (k - 96)];
    }
    int rg = tid >> 4;              // 0..15 (2 rows each)
    int cg = tid & 15;              // 0..15 (6 cols each)
    float acc[12];
    #pragma unroll
    for (int c = 0; c < 12; ++c) acc[c] = 0.0f;
    for (int kc = 0; kc < 3; ++kc) {
        __syncthreads();
        {
            float4* Wt4 = (float4*)Wt;
            const float4* Wg4 = (const float4*)(W + kc * 64 * 96);
            for (int i = tid; i < 1536; i += 256) Wt4[i] = Wg4[i];
        }
        __syncthreads();
        #pragma unroll 4
        for (int k = 0; k < 64; ++k) {
            float a0 = xs[rg * 2 + 0][kc * 64 + k];
            float a1 = xs[rg * 2 + 1][kc * 64 + k];
            #pragma unroll
            for (int c = 0; c < 6; ++c) {
                float wv_ = Wt[k * 96 + cg * 6 + c];
                acc[c]     = fmaf(a0, wv_, acc[c]);
                acc[6 + c] = fmaf(a1, wv_, acc[6 + c]);
            }
        }
    }
    // epilogue into LDS (cols 0..95 don't overlap kc=2's read range 128..191)
    #pragma unroll
    for (int i = 0; i < 2; ++i) {
        #pragma unroll
        for (int c = 0; c < 6; ++c) {
            int col = cg * 6 + c;
            float v = acc[i * 6 + c] + bias[col];
            if (m == 3) v = 1.0f / (1.0f + expf(-v));
            xs[rg * 2 + i][col] = v;
        }
    }
    __syncthreads();
    // coalesced store: per head h, 32 rows * 8 floats = contiguous 64 float4
    float4* out4 = (float4*)outp;
    for (int j = tid; j < 768; j += 256) {
        int h = j >> 6, idx = j & 63;
        int r = idx >> 1, half = idx & 1;
        float4 v = *(const float4*)&xs[r][h * 8 + half * 4];
        out4[(((size_t)b * Hn + h) * Nn + n0) * 2 + idx] = v;
    }
}

// Pass 3: split-KV attention, head-major. 8 waves/block, 128 keys/wave,
// 4-key groups; K/V time-share one 8xfloat4 register block (VGPR diet ->
// 3 blocks/CU, 6 waves/SIMD, 768 blocks = exactly one occupancy round).
// Each block additionally zeroes one out_wm chunk [0, 768) at start;
// the stores drain under the flash-attention VALU work.
__global__ __launch_bounds__(512, 6) void attn_kernel(
        const float* __restrict__ qp, const float* __restrict__ kp,
        const float* __restrict__ vp, const float* __restrict__ gp,
        float* __restrict__ ao,
        const float* __restrict__ dist, const float* __restrict__ sigma,
        const float* __restrict__ beta, float* __restrict__ out_wm) {
    __shared__ float sm[512], sl[512];
    __shared__ float sacc[512][9];
    __shared__ int s_act[256];
    int tid = threadIdx.x;
    zero_wm_chunk(blockIdx.y * 16 + blockIdx.x, dist, sigma, beta, out_wm, tid, 512, s_act);
    int bh = blockIdx.y;                    // b*H + h
    int lane = tid & 63;
    int w = __builtin_amdgcn_readfirstlane(tid >> 6);
    int n = blockIdx.x * 64 + lane;
    size_t hb = (size_t)bh * (Nn * 8);
    size_t qoff = hb + (size_t)n * 8;

    const float scale = 0.35355339059327376f;  // 1/sqrt(8)
    float4 q0 = *(const float4*)&qp[qoff];
    float4 q1 = *(const float4*)&qp[qoff + 4];
    q0.x *= scale; q0.y *= scale; q0.z *= scale; q0.w *= scale;
    q1.x *= scale; q1.y *= scale; q1.z *= scale; q1.w *= scale;

    const float4* kc4 = (const float4*)(kp + hb) + (size_t)w * 256;  // 128 keys
    const float4* vc4 = (const float4*)(vp + hb) + (size_t)w * 256;

    float m = -1e30f, l = 0.0f;
    float a0 = 0, a1 = 0, a2 = 0, a3 = 0, a4 = 0, a5 = 0, a6 = 0, a7 = 0;
    for (int g = 0; g < 32; ++g) {          // 4 keys per group
        float4 T[8];
        #pragma unroll
        for (int i = 0; i < 8; ++i) T[i] = kc4[g * 8 + i];   // K group
        float s[4];
        #pragma unroll
        for (int jj = 0; jj < 4; ++jj) {
            float4 k0 = T[jj * 2], k1 = T[jj * 2 + 1];
            s[jj] = q0.x * k0.x + q0.y * k0.y + q0.z * k0.z + q0.w * k0.w +
                    q1.x * k1.x + q1.y * k1.y + q1.z * k1.z + q1.w * k1.w;
        }
        #pragma unroll
        for (int i = 0; i < 8; ++i) T[i] = vc4[g * 8 + i];   // reuse regs: V group
        float mx = fmaxf(fmaxf(s[0], s[1]), fmaxf(s[2], s[3]));
        float nm = fmaxf(m, mx);
        float corr = __expf(m - nm);
        float p[4];
        #pragma unroll
        for (int jj = 0; jj < 4; ++jj) p[jj] = __expf(s[jj] - nm);
        l = l * corr + (p[0] + p[1]) + (p[2] + p[3]);
        a0 *= corr; a1 *= corr; a2 *= corr; a3 *= corr;
        a4 *= corr; a5 *= corr; a6 *= corr; a7 *= corr;
        #pragma unroll
        for (int jj = 0; jj < 4; ++jj) {
            float4 v0 = T[jj * 2], v1 = T[jj * 2 + 1];
            a0 = fmaf(p[jj], v0.x, a0);  a1 = fmaf(p[jj], v0.y, a1);
            a2 = fmaf(p[jj], v0.z, a2);  a3 = fmaf(p[jj], v0.w, a3);
            a4 = fmaf(p[jj], v1.x, a4);  a5 = fmaf(p[jj], v1.y, a5);
            a6 = fmaf(p[jj], v1.z, a6);  a7 = fmaf(p[jj], v1.w, a7);
        }
        m = nm;
    }
    sm[tid] = m;
    sl[tid] = l;
    sacc[tid][0] = a0; sacc[tid][1] = a1; sacc[tid][2] = a2; sacc[tid][3] = a3;
    sacc[tid][4] = a4; sacc[tid][5] = a5; sacc[tid][6] = a6; sacc[tid][7] = a7;
    __syncthreads();
    if (tid < 64) {
        float M = sm[tid];
        #pragma unroll
        for (int i = 1; i < 8; ++i) M = fmaxf(M, sm[tid + 64 * i]);
        float L = 0.0f;
        float o[8] = {0, 0, 0, 0, 0, 0, 0, 0};
        #pragma unroll
        for (int i = 0; i < 8; ++i) {
            float e = __expf(sm[tid + 64 * i] - M);
            L = fmaf(sl[tid + 64 * i], e, L);
            #pragma unroll
            for (int d = 0; d < 8; ++d)
                o[d] = fmaf(sacc[tid + 64 * i][d], e, o[d]);
        }
        float invL = 1.0f / L;
        float4 g0 = *(const float4*)&gp[qoff];
        float4 g1v = *(const float4*)&gp[qoff + 4];
        float4 r0 = make_float4(o[0] * invL * g0.x, o[1] * invL * g0.y,
                                o[2] * invL * g0.z, o[3] * invL * g0.w);
        float4 r1 = make_float4(o[4] * invL * g1v.x, o[5] * invL * g1v.y,
                                o[6] * invL * g1v.z, o[7] * invL * g1v.w);
        *(float4*)&ao[qoff] = r0;
        *(float4*)&ao[qoff + 4] = r1;
    }
}

// Pass 4: out @ Wo + bo -> GELU -> LayerNorm. 512 thr, 32 rows/block,
// coalesced float4 gather of head-major ao via LDS.
// Each block additionally zeroes one out_wm chunk [896, 1024).
__global__ __launch_bounds__(512) void out_kernel(
        const float* __restrict__ ao, const float* __restrict__ Wo,
        const float* __restrict__ bo, const float* __restrict__ g2,
        const float* __restrict__ b2, float* __restrict__ out0,
        const float* __restrict__ dist, const float* __restrict__ sigma,
        const float* __restrict__ beta, float* __restrict__ out_wm) {
    __shared__ float Wsh[96 * 96];
    __shared__ float as_[32][104];   // row byte-stride 416 = 26*16 (16B aligned)
    __shared__ int s_act[256];
    int tid = threadIdx.x;
    zero_wm_chunk(896 + blockIdx.x, dist, sigma, beta, out_wm, tid, 512, s_act);
    int row0 = blockIdx.x * 32;
    int b = row0 >> 10, n0 = row0 & 1023;
    {
        float4* W4 = (float4*)Wsh;
        const float4* Wg4 = (const float4*)Wo;
        for (int i = tid; i < 2304; i += 512) W4[i] = Wg4[i];
    }
    const float4* ao4 = (const float4*)ao;
    for (int j = tid; j < 768; j += 512) {
        int h = j >> 6, idx = j & 63;
        int r = idx >> 1, half = idx & 1;
        float4 v = ao4[(((size_t)b * Hn + h) * Nn + n0) * 2 + idx];
        *(float4*)&as_[r][h * 8 + half * 4] = v;
    }
    __syncthreads();
    int r = tid >> 4, cg = tid & 15;   // 32 rows, 6 cols per thread
    float acc[6];
    #pragma unroll
    for (int c = 0; c < 6; ++c) acc[c] = 0.0f;
    for (int k = 0; k < 96; ++k) {
        float a = as_[r][k];
        #pragma unroll
        for (int c = 0; c < 6; ++c)
            acc[c] = fmaf(a, Wsh[k * 96 + cg * 6 + c], acc[c]);
    }
    float yv[6];
    float sum = 0.0f, sum2 = 0.0f;
    #pragma unroll
    for (int c = 0; c < 6; ++c) {
        float t = acc[c] + bo[cg * 6 + c];
        float g = gelu_exact(t);
        yv[c] = g;
        sum += g; sum2 += g * g;
    }
    #pragma unroll
    for (int off = 1; off < 16; off <<= 1) {
        sum  += __shfl_xor(sum, off);
        sum2 += __shfl_xor(sum2, off);
    }
    float mean = sum * (1.0f / 96.0f);
    float var  = sum2 * (1.0f / 96.0f) - mean * mean;
    float rs   = rsqrtf(var + 1e-3f);
    size_t row = row0 + r;
    #pragma unroll
    for (int c = 0; c < 6; ++c)
        out0[row * 96 + cg * 6 + c] = (yv[c] - mean) * rs * g2[cg * 6 + c] + b2[cg * 6 + c];
}

extern "C" void kernel_launch(void* const* d_in, const int* in_sizes, int n_in,
                              void* d_out, int out_size, void* d_ws, size_t ws_size,
                              hipStream_t stream) {
    const float* nodes = (const float*)d_in[0];
    const float* ef    = (const float*)d_in[1];
    const float* dist  = (const float*)d_in[2];
    const int*   edges = (const int*)d_in[3];
    const float* Wm = (const float*)d_in[4];
    const float* bm = (const float*)d_in[5];
    const float* g1 = (const float*)d_in[6];
    const float* b1 = (const float*)d_in[7];
    const float* Wq = (const float*)d_in[8];
    const float* bq = (const float*)d_in[9];
    const float* Wk = (const float*)d_in[10];
    const float* bk = (const float*)d_in[11];
    const float* Wv = (const float*)d_in[12];
    const float* bv = (const float*)d_in[13];
    const float* Wg = (const float*)d_in[14];
    const float* bg = (const float*)d_in[15];
    const float* Wo = (const float*)d_in[16];
    const float* bo = (const float*)d_in[17];
    const float* g2 = (const float*)d_in[18];
    const float* b2 = (const float*)d_in[19];
    const float* sigma = (const float*)d_in[20];
    const float* beta  = (const float*)d_in[21];

    float* out = (float*)d_out;
    float* ws  = (float*)d_ws;

    float* agg  = ws + WS_AGG;
    float* qb   = ws + WS_Q;
    float* kb   = ws + WS_K;
    float* vb   = ws + WS_V;
    float* gwb  = ws + WS_G;
    float* aob  = ws + WS_AO;

    zero_kernel<<<192, 256, 0, stream>>>(agg);

    scanmsg_kernel<<<Bn * En / 256, 256, 0, stream>>>(
        dist, edges, sigma, beta, nodes, ef, Wm, bm, g1, b1,
        out + OUT_DIST, out + OUT_EDGE, out + OUT_WM, agg);

    dim3 gp_(128, 4);
    proj_kernel<<<gp_, 256, 0, stream>>>(
        nodes, agg, Wq, bq, Wk, bk, Wv, bv, Wg, bg, qb, kb, vb, gwb,
        dist, sigma, beta, out + OUT_WM);

    dim3 ga(16, Bn * Hn);
    attn_kernel<<<ga, 512, 0, stream>>>(qb, kb, vb, gwb, aob,
                                        dist, sigma, beta, out + OUT_WM);

    out_kernel<<<Bn * Nn / 32, 512, 0, stream>>>(aob, Wo, bo, g2, b2, out + OUT_UPD,
                                                 dist, sigma, beta, out + OUT_WM);
}